// Round 19
// baseline (99.800 us; speedup 1.0000x reference)
//
#include <hip/hip_runtime.h>

#define DEVI __device__ __forceinline__

typedef __attribute__((ext_vector_type(8))) short short8;
typedef __attribute__((ext_vector_type(4))) short s16x4;
typedef __attribute__((ext_vector_type(4))) float f32x4;
typedef __attribute__((ext_vector_type(16))) float f32x16;

DEVI unsigned short f32_to_bf16(float f) {
  unsigned int u = __float_as_uint(f);
  u += 0x7fffu + ((u >> 16) & 1u);
  return (unsigned short)(u >> 16);
}
DEVI float bf16_to_f32(unsigned short h) {
  return __uint_as_float(((unsigned int)h) << 16);
}

DEVI void gld_lds16(const void* g, void* l) {
  __builtin_amdgcn_global_load_lds(
      (__attribute__((address_space(1))) void*)(g),
      (__attribute__((address_space(3))) void*)(l), 16, 0, 0);
}

// ------------- merged prep: x cast + W_qkv transpose + W_out transpose ------
// grid.x: [0,1536) cast x; [1536,3264) Wq_t (24x72); [3264,3840) Wo_t (24x24)
__global__ __launch_bounds__(256) void k_prep(const float* __restrict__ x,
                                              const float* __restrict__ Wq,
                                              const float* __restrict__ Wo,
                                              unsigned short* __restrict__ Xb,
                                              unsigned short* __restrict__ Wq_t,
                                              unsigned short* __restrict__ Wo_t) {
  int blk = blockIdx.x;
  int tid = threadIdx.x;
  if (blk < 1536) {
    int i = blk * 256 + tid;
    const float* src = x + (size_t)i * 8;
    short8 v;
#pragma unroll
    for (int j = 0; j < 8; ++j) v[j] = (short)f32_to_bf16(src[j]);
    *(short8*)&Xb[(size_t)i * 8] = v;
    return;
  }
  const float* W;
  unsigned short* Wt;
  int kt, nt, K, N;
  if (blk < 3264) {
    int idx = blk - 1536;
    kt = idx % 24;
    nt = idx / 24;
    W = Wq;
    Wt = Wq_t;
    K = 768;
    N = 2304;
  } else {
    int idx = blk - 3264;
    kt = idx % 24;
    nt = idx / 24;
    W = Wo;
    Wt = Wo_t;
    K = 768;
    N = 768;
  }
  __shared__ float t[32][33];
#pragma unroll
  for (int p = 0; p < 4; ++p) {
    int idx = tid + p * 256;
    int rr = idx >> 5, cc = idx & 31;
    t[rr][cc] = W[(size_t)(kt * 32 + rr) * N + nt * 32 + cc];
  }
  __syncthreads();
#pragma unroll
  for (int p = 0; p < 4; ++p) {
    int idx = tid + p * 256;
    int rn = idx >> 5, ck = idx & 31;
    Wt[(size_t)(nt * 32 + rn) * K + kt * 32 + ck] = f32_to_bf16(t[ck][rn]);
  }
}

// ---------------- GEMM1: 128x64 tile, QKV scatter epilogue ------------------
__global__ __launch_bounds__(256) void k_gemm_qkv(const unsigned short* __restrict__ A,
                                                  const unsigned short* __restrict__ Bt,
                                                  const float* __restrict__ bias,
                                                  int M, int N, int K,
                                                  unsigned short* __restrict__ Qo,
                                                  unsigned short* __restrict__ Ko,
                                                  unsigned short* __restrict__ Vt) {
  __shared__ __align__(16) unsigned short As[128 * 32];
  __shared__ __align__(16) unsigned short Bs[64 * 32];
  int tid = threadIdx.x;
  int tm = blockIdx.x, tn = blockIdx.y;
  int lane = tid & 63, wid = tid >> 6;
  int g = lane >> 4, lr = lane & 15;
  f32x4 acc[2][4] = {};
  int srow = tid >> 2;
  int scol = (tid & 3) * 8;
  const unsigned short* Ab = A + (size_t)tm * 128 * K;
  const unsigned short* Bb = Bt + (size_t)tn * 64 * K;
  for (int k0 = 0; k0 < K; k0 += 32) {
    gld_lds16(Ab + (size_t)srow * K + k0 + scol, &As[srow * 32 + scol]);
    gld_lds16(Ab + (size_t)(srow + 64) * K + k0 + scol, &As[(srow + 64) * 32 + scol]);
    gld_lds16(Bb + (size_t)srow * K + k0 + scol, &Bs[srow * 32 + scol]);
    __syncthreads();
    short8 a[2], b[4];
#pragma unroll
    for (int m = 0; m < 2; ++m)
      a[m] = *(const short8*)&As[(wid * 32 + m * 16 + lr) * 32 + g * 8];
#pragma unroll
    for (int n = 0; n < 4; ++n)
      b[n] = *(const short8*)&Bs[(n * 16 + lr) * 32 + g * 8];
#pragma unroll
    for (int m = 0; m < 2; ++m)
#pragma unroll
      for (int n = 0; n < 4; ++n)
        acc[m][n] = __builtin_amdgcn_mfma_f32_16x16x32_bf16(a[m], b[n], acc[m][n], 0, 0, 0);
    __syncthreads();
  }
  const float QSCALE = 0.125f * 1.4426950408889634f;
  int sec = tn / 12;              // 0=Q, 1=K, 2=V (uniform per block)
  int cb = tn * 64 - sec * 768;   // section-local col base
#pragma unroll
  for (int m = 0; m < 2; ++m) {
#pragma unroll
    for (int n = 0; n < 4; ++n) {
      int c = cb + n * 16 + lr;
      int hh = c >> 6, d = c & 63;
      float bv = bias[tn * 64 + n * 16 + lr];
      int rowb = tm * 128 + wid * 32 + m * 16 + g * 4;
      int bb = rowb >> 11, nn = rowb & 2047;
      int bh = bb * 12 + hh;
      if (sec == 2) {
        s16x4 v4;
#pragma unroll
        for (int j = 0; j < 4; ++j) v4[j] = (short)f32_to_bf16(acc[m][n][j] + bv);
        *(s16x4*)&Vt[((size_t)bh * 64 + d) * 2048 + nn] = v4;
      } else {
        unsigned short* dst0 = (sec == 0) ? Qo : Ko;
        float sc = (sec == 0) ? QSCALE : 1.0f;
#pragma unroll
        for (int j = 0; j < 4; ++j) {
          size_t dst = (((size_t)bh << 11) + nn + j) * 64 + d;
          dst0[dst] = f32_to_bf16((acc[m][n][j] + bv) * sc);
        }
      }
    }
  }
}

// ---------------- GEMM2: 64x64 tile, grid (64,12)=768 blocks ----------------
__global__ __launch_bounds__(256) void k_gemm2(const unsigned short* __restrict__ A,
                                               const unsigned short* __restrict__ Bt,
                                               const float* __restrict__ bias,
                                               float* __restrict__ C,
                                               int M, int N, int K) {
  __shared__ __align__(16) unsigned short As[64 * 32];
  __shared__ __align__(16) unsigned short Bs[64 * 32];
  int tid = threadIdx.x;
  int tm = blockIdx.x, tn = blockIdx.y;
  int lane = tid & 63, wid = tid >> 6;
  int wr = wid >> 1, wc = wid & 1;
  int g = lane >> 4, lr = lane & 15;
  f32x4 acc[2][2] = {};
  int srow = tid >> 2;
  int scol = (tid & 3) * 8;
  const unsigned short* Ab = A + (size_t)tm * 64 * K;
  const unsigned short* Bb = Bt + (size_t)tn * 64 * K;
  for (int k0 = 0; k0 < K; k0 += 32) {
    gld_lds16(Ab + (size_t)srow * K + k0 + scol, &As[srow * 32 + scol]);
    gld_lds16(Bb + (size_t)srow * K + k0 + scol, &Bs[srow * 32 + scol]);
    __syncthreads();
    short8 a[2], b[2];
#pragma unroll
    for (int m = 0; m < 2; ++m)
      a[m] = *(const short8*)&As[(wr * 32 + m * 16 + lr) * 32 + g * 8];
#pragma unroll
    for (int n = 0; n < 2; ++n)
      b[n] = *(const short8*)&Bs[(wc * 32 + n * 16 + lr) * 32 + g * 8];
#pragma unroll
    for (int m = 0; m < 2; ++m)
#pragma unroll
      for (int n = 0; n < 2; ++n)
        acc[m][n] = __builtin_amdgcn_mfma_f32_16x16x32_bf16(a[m], b[n], acc[m][n], 0, 0, 0);
    __syncthreads();
  }
#pragma unroll
  for (int m = 0; m < 2; ++m) {
#pragma unroll
    for (int n = 0; n < 2; ++n) {
      int col = tn * 64 + wc * 32 + n * 16 + lr;
      float bv = bias[col];
#pragma unroll
      for (int j = 0; j < 4; ++j) {
        int row = tm * 64 + wr * 32 + m * 16 + g * 4 + j;
        C[(size_t)row * N + col] = acc[m][n][j] + bv;
      }
    }
  }
}

// ------------- flash attention: split-k ACROSS blocks (z = KV half) ---------
// Grid (24,32,2) = 1536 blocks -> 5 blocks/CU (LDS 32KB), ~20 waves/CU.
// Each block: 64 q x 1024 KV, 4 waves (qh x kh), dbuf, in-register P.
// Writes UNNORMALIZED partial O (bf16) + l per q; k_merge normalizes.

#define ATTN_STAGE(KSB, VSB, T)                                                          \
  {                                                                                      \
    int kv0 = (T) * 64;                                                                  \
    _Pragma("unroll") for (int it = 0; it < 2; ++it) {                                   \
      int L = tid + it * 256;                                                            \
      int rw = L >> 3, s7 = L & 7;                                                       \
      gld_lds16(Kb + (size_t)(khead + kv0 + rw) * 64 + ((s7 ^ (rw & 7)) * 8),            \
                &KSB[L * 8]);                                                            \
      gld_lds16(Vt + (size_t)(vhead + rw) * 2048 + kv0 + ((s7 ^ (rw & 7)) * 8),          \
                &VSB[L * 8]);                                                            \
    }                                                                                    \
  }

#define BUILD_PA(S)                                                                      \
  {                                                                                      \
    unsigned int b0, a0, e0, c0;                                                         \
    asm("v_cvt_pk_bf16_f32 %0, %1, %2" : "=v"(b0) : "v"(S[0]), "v"(S[1]));               \
    asm("v_cvt_pk_bf16_f32 %0, %1, %2" : "=v"(a0) : "v"(S[4]), "v"(S[5]));               \
    asm("v_permlane32_swap_b32 %0, %1" : "+v"(b0), "+v"(a0));                            \
    asm("v_cvt_pk_bf16_f32 %0, %1, %2" : "=v"(e0) : "v"(S[2]), "v"(S[3]));               \
    asm("v_cvt_pk_bf16_f32 %0, %1, %2" : "=v"(c0) : "v"(S[6]), "v"(S[7]));               \
    asm("v_permlane32_swap_b32 %0, %1" : "+v"(e0), "+v"(c0));                            \
    paw[0][0] = b0; paw[0][1] = e0; paw[0][2] = a0; paw[0][3] = c0;                      \
    unsigned int b1, a1, e1, c1;                                                         \
    asm("v_cvt_pk_bf16_f32 %0, %1, %2" : "=v"(b1) : "v"(S[8]), "v"(S[9]));               \
    asm("v_cvt_pk_bf16_f32 %0, %1, %2" : "=v"(a1) : "v"(S[12]), "v"(S[13]));             \
    asm("v_permlane32_swap_b32 %0, %1" : "+v"(b1), "+v"(a1));                            \
    asm("v_cvt_pk_bf16_f32 %0, %1, %2" : "=v"(e1) : "v"(S[10]), "v"(S[11]));             \
    asm("v_cvt_pk_bf16_f32 %0, %1, %2" : "=v"(c1) : "v"(S[14]), "v"(S[15]));             \
    asm("v_permlane32_swap_b32 %0, %1" : "+v"(e1), "+v"(c1));                            \
    paw[1][0] = b1; paw[1][1] = e1; paw[1][2] = a1; paw[1][3] = c1;                      \
  }

#define PROC_TILE(KSB, VSB)                                                              \
  {                                                                                      \
    f32x16 sa = {};                                                                      \
    __builtin_amdgcn_s_setprio(1);                                                       \
    _Pragma("unroll") for (int ds = 0; ds < 4; ++ds) {                                   \
      short8 kf = *(const short8*)&KSB[(kh * 32 + ln31) * 64 + (((ds * 2 + hi) ^ ln7) * 8)]; \
      sa = __builtin_amdgcn_mfma_f32_32x32x16_bf16(kf, qf[ds], sa, 0, 0, 0);             \
    }                                                                                    \
    __builtin_amdgcn_s_setprio(0);                                                       \
    _Pragma("unroll") for (int i = 0; i < 16; ++i) {                                     \
      float pv = exp2f(sa[i]);                                                           \
      sa[i] = pv;                                                                        \
      lrun += pv;                                                                        \
    }                                                                                    \
    unsigned int paw[2][4];                                                              \
    BUILD_PA(sa)                                                                         \
    __builtin_amdgcn_s_setprio(1);                                                       \
    _Pragma("unroll") for (int kl = 0; kl < 2; ++kl) {                                   \
      union {                                                                            \
        unsigned int u[4];                                                               \
        short8 s8;                                                                       \
      } pu;                                                                              \
      pu.u[0] = paw[kl][0];                                                              \
      pu.u[1] = paw[kl][1];                                                              \
      pu.u[2] = paw[kl][2];                                                              \
      pu.u[3] = paw[kl][3];                                                              \
      int ksg = kh * 2 + kl;                                                             \
      short8 vb0 = *(const short8*)&VSB[ln31 * 64 + (((ksg * 2 + hi) ^ ln7) * 8)];       \
      short8 vb1 = *(const short8*)&VSB[(32 + ln31) * 64 + (((ksg * 2 + hi) ^ ln7) * 8)]; \
      oacc0 = __builtin_amdgcn_mfma_f32_32x32x16_bf16(pu.s8, vb0, oacc0, 0, 0, 0);       \
      oacc1 = __builtin_amdgcn_mfma_f32_32x32x16_bf16(pu.s8, vb1, oacc1, 0, 0, 0);       \
    }                                                                                    \
    __builtin_amdgcn_s_setprio(0);                                                       \
  }

__global__ __launch_bounds__(256, 4) void k_attn(const unsigned short* __restrict__ Qb,
                                                 const unsigned short* __restrict__ Kb,
                                                 const unsigned short* __restrict__ Vt,
                                                 unsigned short* __restrict__ Op0,
                                                 unsigned short* __restrict__ Op1,
                                                 float* __restrict__ Lout) {
  int bh = blockIdx.x;  // 24
  int qb = blockIdx.y;  // 32
  int z = blockIdx.z;   // 2 (KV half)
  int b = bh / 12;
  __shared__ __align__(16) unsigned short LDSbuf[4 * 64 * 64];
  unsigned short* Ks0 = LDSbuf;
  unsigned short* Vs0 = LDSbuf + 64 * 64;
  unsigned short* Ks1 = LDSbuf + 2 * 64 * 64;
  unsigned short* Vs1 = LDSbuf + 3 * 64 * 64;
  int tid = threadIdx.x;
  int wid = tid >> 6, lane = tid & 63;
  int qh = wid >> 1, kh = wid & 1;
  int ln31 = lane & 31, hi = lane >> 5, ln7 = lane & 7;
  int khead = bh * 2048;
  int vhead = bh * 64;
  int q0 = qb * 64 + qh * 32;
  int t0 = z * 16;  // this block's 16 tiles of 64 KV

  short8 qf[4];
#pragma unroll
  for (int ds = 0; ds < 4; ++ds)
    qf[ds] = *(const short8*)&Qb[(size_t)(khead + q0 + ln31) * 64 + ds * 16 + hi * 8];

  float lrun = 0.f;
  f32x16 oacc0 = {}, oacc1 = {};

  ATTN_STAGE(Ks0, Vs0, t0);
  __syncthreads();
#pragma unroll 1
  for (int tt = 0; tt < 8; ++tt) {
    ATTN_STAGE(Ks1, Vs1, t0 + 2 * tt + 1);
    PROC_TILE(Ks0, Vs0);
    __syncthreads();
    if (tt < 7) ATTN_STAGE(Ks0, Vs0, t0 + 2 * tt + 2);
    PROC_TILE(Ks1, Vs1);
    __syncthreads();
  }

  // combine hi-halves (k sub-groups within this wave's k-half; same q)
  lrun += __shfl_xor(lrun, 32, 64);

  // merge kh pairs via LDS scratch (reuse staging buffers)
  float* scr = (float*)LDSbuf;  // [2 qh][64 lane][33]
  if (kh == 1) {
    float* p = scr + (size_t)(qh * 64 + lane) * 33;
#pragma unroll
    for (int i = 0; i < 16; ++i) {
      p[i] = oacc0[i];
      p[16 + i] = oacc1[i];
    }
    p[32] = lrun;
  }
  __syncthreads();
  if (kh == 0) {
    float* p = scr + (size_t)(qh * 64 + lane) * 33;
#pragma unroll
    for (int i = 0; i < 16; ++i) {
      oacc0[i] += p[i];
      oacc1[i] += p[16 + i];
    }
    lrun += p[32];
    unsigned short* Op = z ? Op1 : Op0;
    int h = bh - b * 12;
#pragma unroll
    for (int r = 0; r < 16; ++r) {
      int qrow = (r & 3) + 8 * (r >> 2) + 4 * hi;
      int grow = b * 2048 + q0 + qrow;
      int colb = h * 64 + ln31;
      Op[(size_t)grow * 768 + colb] = f32_to_bf16(oacc0[r]);
      Op[(size_t)grow * 768 + colb + 32] = f32_to_bf16(oacc1[r]);
    }
    if (hi == 0) Lout[((size_t)z * 24 + bh) * 2048 + q0 + ln31] = lrun;
  }
}

// ------------- merge: Xh = (O0+O1) / (l0+l1) -> bf16 ------------------------
// 4096 rows x 768 cols; thread handles 8 cols (same head). 1536 blocks.
__global__ __launch_bounds__(256) void k_merge(const unsigned short* __restrict__ Op0,
                                               const unsigned short* __restrict__ Op1,
                                               const float* __restrict__ Lbuf,
                                               unsigned short* __restrict__ Xh) {
  int idx = blockIdx.x * 256 + threadIdx.x;  // [0, 4096*96)
  int row = idx / 96;
  int c0 = (idx - row * 96) * 8;
  int b = row >> 11, n = row & 2047;
  int h = c0 >> 6;
  int bh = b * 12 + h;
  float l0 = Lbuf[((size_t)0 * 24 + bh) * 2048 + n];
  float l1 = Lbuf[((size_t)1 * 24 + bh) * 2048 + n];
  float inv = 1.0f / (l0 + l1);
  size_t base = (size_t)row * 768 + c0;
  short8 o0 = *(const short8*)&Op0[base];
  short8 o1 = *(const short8*)&Op1[base];
  short8 w;
#pragma unroll
  for (int j = 0; j < 8; ++j) {
    float v = (bf16_to_f32((unsigned short)o0[j]) + bf16_to_f32((unsigned short)o1[j])) * inv;
    w[j] = (short)f32_to_bf16(v);
  }
  *(short8*)&Xh[base] = w;
}

// ---------------- launch ----------------
extern "C" void kernel_launch(void* const* d_in, const int* in_sizes, int n_in,
                              void* d_out, int out_size, void* d_ws, size_t ws_size,
                              hipStream_t stream) {
  const float* x = (const float*)d_in[0];      // [2,2048,768]
  const float* W_qkv = (const float*)d_in[1];  // [768,2304]
  const float* b_qkv = (const float*)d_in[2];  // [2304]
  const float* W_out = (const float*)d_in[3];  // [768,768]
  const float* b_out = (const float*)d_in[4];  // [768]
  float* out = (float*)d_out;                  // [4096,768]
  char* ws = (char*)d_ws;

  unsigned short* Xh = (unsigned short*)(ws + 0);           // 4096x768 bf16 (merged H)
  unsigned short* Xb = (unsigned short*)(ws + 18874368);    // 4096x768 bf16 (x cast)
  unsigned short* Wq_t = (unsigned short*)(ws + 25165824);  // 2304x768 bf16
  unsigned short* Wo_t = (unsigned short*)(ws + 28704768);  // 768x768 bf16
  unsigned short* Qb = (unsigned short*)(ws + 32243712);    // 24x2048x64 (pre-scaled)
  unsigned short* Kb = (unsigned short*)(ws + 38535168);    // 24x2048x64
  unsigned short* Op0 = (unsigned short*)(ws + 44826624);   // 4096x768 bf16 partial O (z=0)
  unsigned short* Vt = (unsigned short*)(ws + 51118080);    // 24x64x2048
  unsigned short* Op1 = (unsigned short*)(ws + 57409536);   // 4096x768 bf16 partial O (z=1)
  float* Lbuf = (float*)(ws + 63700992);                    // [2][24][2048] f32

  k_prep<<<3840, 256, 0, stream>>>(x, W_qkv, W_out, Xb, Wq_t, Wo_t);
  k_gemm_qkv<<<dim3(32, 36), 256, 0, stream>>>(Xb, Wq_t, b_qkv, 4096, 2304, 768, Qb, Kb, Vt);
  k_attn<<<dim3(24, 32, 2), 256, 0, stream>>>(Qb, Kb, Vt, Op0, Op1, Lbuf);
  k_merge<<<1536, 256, 0, stream>>>(Op0, Op1, Lbuf, Xh);
  k_gemm2<<<dim3(64, 12), 256, 0, stream>>>(Xh, Wo_t, b_out, out, 4096, 768, 768);
}

// Round 20
// 96.786 us; speedup vs baseline: 1.0311x; 1.0311x over previous
//
#include <hip/hip_runtime.h>

#define DEVI __device__ __forceinline__

typedef __attribute__((ext_vector_type(8))) short short8;
typedef __attribute__((ext_vector_type(4))) short s16x4;
typedef __attribute__((ext_vector_type(4))) float f32x4;
typedef __attribute__((ext_vector_type(16))) float f32x16;

DEVI unsigned short f32_to_bf16(float f) {
  unsigned int u = __float_as_uint(f);
  u += 0x7fffu + ((u >> 16) & 1u);
  return (unsigned short)(u >> 16);
}
DEVI float bf16_to_f32(unsigned short h) {
  return __uint_as_float(((unsigned int)h) << 16);
}

DEVI void gld_lds16(const void* g, void* l) {
  __builtin_amdgcn_global_load_lds(
      (__attribute__((address_space(1))) void*)(g),
      (__attribute__((address_space(3))) void*)(l), 16, 0, 0);
}

// ------------- merged prep: x cast + W_qkv transpose + W_out transpose ------
// grid.x: [0,1536) cast x; [1536,3264) Wq_t (24x72); [3264,3840) Wo_t (24x24)
__global__ __launch_bounds__(256) void k_prep(const float* __restrict__ x,
                                              const float* __restrict__ Wq,
                                              const float* __restrict__ Wo,
                                              unsigned short* __restrict__ Xb,
                                              unsigned short* __restrict__ Wq_t,
                                              unsigned short* __restrict__ Wo_t) {
  int blk = blockIdx.x;
  int tid = threadIdx.x;
  if (blk < 1536) {
    int i = blk * 256 + tid;
    const float* src = x + (size_t)i * 8;
    short8 v;
#pragma unroll
    for (int j = 0; j < 8; ++j) v[j] = (short)f32_to_bf16(src[j]);
    *(short8*)&Xb[(size_t)i * 8] = v;
    return;
  }
  const float* W;
  unsigned short* Wt;
  int kt, nt, K, N;
  if (blk < 3264) {
    int idx = blk - 1536;
    kt = idx % 24;
    nt = idx / 24;
    W = Wq;
    Wt = Wq_t;
    K = 768;
    N = 2304;
  } else {
    int idx = blk - 3264;
    kt = idx % 24;
    nt = idx / 24;
    W = Wo;
    Wt = Wo_t;
    K = 768;
    N = 768;
  }
  __shared__ float t[32][33];
#pragma unroll
  for (int p = 0; p < 4; ++p) {
    int idx = tid + p * 256;
    int rr = idx >> 5, cc = idx & 31;
    t[rr][cc] = W[(size_t)(kt * 32 + rr) * N + nt * 32 + cc];
  }
  __syncthreads();
#pragma unroll
  for (int p = 0; p < 4; ++p) {
    int idx = tid + p * 256;
    int rn = idx >> 5, ck = idx & 31;
    Wt[(size_t)(nt * 32 + rn) * K + kt * 32 + ck] = f32_to_bf16(t[ck][rn]);
  }
}

// ---------------- GEMM1: 128x64 tile, QKV scatter epilogue ------------------
__global__ __launch_bounds__(256) void k_gemm_qkv(const unsigned short* __restrict__ A,
                                                  const unsigned short* __restrict__ Bt,
                                                  const float* __restrict__ bias,
                                                  int M, int N, int K,
                                                  unsigned short* __restrict__ Qo,
                                                  unsigned short* __restrict__ Ko,
                                                  unsigned short* __restrict__ Vt) {
  __shared__ __align__(16) unsigned short As[128 * 32];
  __shared__ __align__(16) unsigned short Bs[64 * 32];
  int tid = threadIdx.x;
  int tm = blockIdx.x, tn = blockIdx.y;
  int lane = tid & 63, wid = tid >> 6;
  int g = lane >> 4, lr = lane & 15;
  f32x4 acc[2][4] = {};
  int srow = tid >> 2;
  int scol = (tid & 3) * 8;
  const unsigned short* Ab = A + (size_t)tm * 128 * K;
  const unsigned short* Bb = Bt + (size_t)tn * 64 * K;
  for (int k0 = 0; k0 < K; k0 += 32) {
    gld_lds16(Ab + (size_t)srow * K + k0 + scol, &As[srow * 32 + scol]);
    gld_lds16(Ab + (size_t)(srow + 64) * K + k0 + scol, &As[(srow + 64) * 32 + scol]);
    gld_lds16(Bb + (size_t)srow * K + k0 + scol, &Bs[srow * 32 + scol]);
    __syncthreads();
    short8 a[2], b[4];
#pragma unroll
    for (int m = 0; m < 2; ++m)
      a[m] = *(const short8*)&As[(wid * 32 + m * 16 + lr) * 32 + g * 8];
#pragma unroll
    for (int n = 0; n < 4; ++n)
      b[n] = *(const short8*)&Bs[(n * 16 + lr) * 32 + g * 8];
#pragma unroll
    for (int m = 0; m < 2; ++m)
#pragma unroll
      for (int n = 0; n < 4; ++n)
        acc[m][n] = __builtin_amdgcn_mfma_f32_16x16x32_bf16(a[m], b[n], acc[m][n], 0, 0, 0);
    __syncthreads();
  }
  const float QSCALE = 0.125f * 1.4426950408889634f;
  int sec = tn / 12;              // 0=Q, 1=K, 2=V (uniform per block)
  int cb = tn * 64 - sec * 768;   // section-local col base
#pragma unroll
  for (int m = 0; m < 2; ++m) {
#pragma unroll
    for (int n = 0; n < 4; ++n) {
      int c = cb + n * 16 + lr;
      int hh = c >> 6, d = c & 63;
      float bv = bias[tn * 64 + n * 16 + lr];
      int rowb = tm * 128 + wid * 32 + m * 16 + g * 4;
      int bb = rowb >> 11, nn = rowb & 2047;
      int bh = bb * 12 + hh;
      if (sec == 2) {
        s16x4 v4;
#pragma unroll
        for (int j = 0; j < 4; ++j) v4[j] = (short)f32_to_bf16(acc[m][n][j] + bv);
        *(s16x4*)&Vt[((size_t)bh * 64 + d) * 2048 + nn] = v4;
      } else {
        unsigned short* dst0 = (sec == 0) ? Qo : Ko;
        float sc = (sec == 0) ? QSCALE : 1.0f;
#pragma unroll
        for (int j = 0; j < 4; ++j) {
          size_t dst = (((size_t)bh << 11) + nn + j) * 64 + d;
          dst0[dst] = f32_to_bf16((acc[m][n][j] + bv) * sc);
        }
      }
    }
  }
}

// ---------------- GEMM2: 64x64 tile, grid (64,12)=768 blocks ----------------
__global__ __launch_bounds__(256) void k_gemm2(const unsigned short* __restrict__ A,
                                               const unsigned short* __restrict__ Bt,
                                               const float* __restrict__ bias,
                                               float* __restrict__ C,
                                               int M, int N, int K) {
  __shared__ __align__(16) unsigned short As[64 * 32];
  __shared__ __align__(16) unsigned short Bs[64 * 32];
  int tid = threadIdx.x;
  int tm = blockIdx.x, tn = blockIdx.y;
  int lane = tid & 63, wid = tid >> 6;
  int wr = wid >> 1, wc = wid & 1;
  int g = lane >> 4, lr = lane & 15;
  f32x4 acc[2][2] = {};
  int srow = tid >> 2;
  int scol = (tid & 3) * 8;
  const unsigned short* Ab = A + (size_t)tm * 64 * K;
  const unsigned short* Bb = Bt + (size_t)tn * 64 * K;
  for (int k0 = 0; k0 < K; k0 += 32) {
    gld_lds16(Ab + (size_t)srow * K + k0 + scol, &As[srow * 32 + scol]);
    gld_lds16(Bb + (size_t)srow * K + k0 + scol, &Bs[srow * 32 + scol]);
    __syncthreads();
    short8 a[2], b[2];
#pragma unroll
    for (int m = 0; m < 2; ++m)
      a[m] = *(const short8*)&As[(wr * 32 + m * 16 + lr) * 32 + g * 8];
#pragma unroll
    for (int n = 0; n < 2; ++n)
      b[n] = *(const short8*)&Bs[(wc * 32 + n * 16 + lr) * 32 + g * 8];
#pragma unroll
    for (int m = 0; m < 2; ++m)
#pragma unroll
      for (int n = 0; n < 2; ++n)
        acc[m][n] = __builtin_amdgcn_mfma_f32_16x16x32_bf16(a[m], b[n], acc[m][n], 0, 0, 0);
    __syncthreads();
  }
#pragma unroll
  for (int m = 0; m < 2; ++m) {
#pragma unroll
    for (int n = 0; n < 2; ++n) {
      int col = tn * 64 + wc * 32 + n * 16 + lr;
      float bv = bias[col];
#pragma unroll
      for (int j = 0; j < 4; ++j) {
        int row = tm * 64 + wr * 32 + m * 16 + g * 4 + j;
        C[(size_t)row * N + col] = acc[m][n][j] + bv;
      }
    }
  }
}

// ------------- flash attention: 32x32 MFMA, in-register P, split-k ----------
// 4 waves x (32 q, 32 k-half), KV tile 64, dbuf. Grid (24,32)=768, LDS 32KB.
// l computed via MFMA ones-column: lacc = mfma(P, ones) gives l[qrow] in
// oacc's C-layout -- no lrun adds, no reduction shuffles, no broadcasts.

#define ATTN_STAGE(KSB, VSB, T)                                                          \
  {                                                                                      \
    int kv0 = (T) * 64;                                                                  \
    _Pragma("unroll") for (int it = 0; it < 2; ++it) {                                   \
      int L = tid + it * 256;                                                            \
      int rw = L >> 3, s7 = L & 7;                                                       \
      gld_lds16(Kb + (size_t)(khead + kv0 + rw) * 64 + ((s7 ^ (rw & 7)) * 8),            \
                &KSB[L * 8]);                                                            \
      gld_lds16(Vt + (size_t)(vhead + rw) * 2048 + kv0 + ((s7 ^ (rw & 7)) * 8),          \
                &VSB[L * 8]);                                                            \
    }                                                                                    \
  }

#define BUILD_PA(S)                                                                      \
  {                                                                                      \
    unsigned int b0, a0, e0, c0;                                                         \
    asm("v_cvt_pk_bf16_f32 %0, %1, %2" : "=v"(b0) : "v"(S[0]), "v"(S[1]));               \
    asm("v_cvt_pk_bf16_f32 %0, %1, %2" : "=v"(a0) : "v"(S[4]), "v"(S[5]));               \
    asm("v_permlane32_swap_b32 %0, %1" : "+v"(b0), "+v"(a0));                            \
    asm("v_cvt_pk_bf16_f32 %0, %1, %2" : "=v"(e0) : "v"(S[2]), "v"(S[3]));               \
    asm("v_cvt_pk_bf16_f32 %0, %1, %2" : "=v"(c0) : "v"(S[6]), "v"(S[7]));               \
    asm("v_permlane32_swap_b32 %0, %1" : "+v"(e0), "+v"(c0));                            \
    paw[0][0] = b0; paw[0][1] = e0; paw[0][2] = a0; paw[0][3] = c0;                      \
    unsigned int b1, a1, e1, c1;                                                         \
    asm("v_cvt_pk_bf16_f32 %0, %1, %2" : "=v"(b1) : "v"(S[8]), "v"(S[9]));               \
    asm("v_cvt_pk_bf16_f32 %0, %1, %2" : "=v"(a1) : "v"(S[12]), "v"(S[13]));             \
    asm("v_permlane32_swap_b32 %0, %1" : "+v"(b1), "+v"(a1));                            \
    asm("v_cvt_pk_bf16_f32 %0, %1, %2" : "=v"(e1) : "v"(S[10]), "v"(S[11]));             \
    asm("v_cvt_pk_bf16_f32 %0, %1, %2" : "=v"(c1) : "v"(S[14]), "v"(S[15]));             \
    asm("v_permlane32_swap_b32 %0, %1" : "+v"(e1), "+v"(c1));                            \
    paw[1][0] = b1; paw[1][1] = e1; paw[1][2] = a1; paw[1][3] = c1;                      \
  }

#define PROC_TILE(KSB, VSB)                                                              \
  {                                                                                      \
    f32x16 sa = {};                                                                      \
    __builtin_amdgcn_s_setprio(1);                                                       \
    _Pragma("unroll") for (int ds = 0; ds < 4; ++ds) {                                   \
      short8 kf = *(const short8*)&KSB[(kh * 32 + ln31) * 64 + (((ds * 2 + hi) ^ ln7) * 8)]; \
      sa = __builtin_amdgcn_mfma_f32_32x32x16_bf16(kf, qf[ds], sa, 0, 0, 0);             \
    }                                                                                    \
    __builtin_amdgcn_s_setprio(0);                                                       \
    _Pragma("unroll") for (int i = 0; i < 16; ++i) sa[i] = exp2f(sa[i]);                 \
    unsigned int paw[2][4];                                                              \
    BUILD_PA(sa)                                                                         \
    __builtin_amdgcn_s_setprio(1);                                                       \
    _Pragma("unroll") for (int kl = 0; kl < 2; ++kl) {                                   \
      union {                                                                            \
        unsigned int u[4];                                                               \
        short8 s8;                                                                       \
      } pu;                                                                              \
      pu.u[0] = paw[kl][0];                                                              \
      pu.u[1] = paw[kl][1];                                                              \
      pu.u[2] = paw[kl][2];                                                              \
      pu.u[3] = paw[kl][3];                                                              \
      int ksg = kh * 2 + kl;                                                             \
      short8 vb0 = *(const short8*)&VSB[ln31 * 64 + (((ksg * 2 + hi) ^ ln7) * 8)];       \
      short8 vb1 = *(const short8*)&VSB[(32 + ln31) * 64 + (((ksg * 2 + hi) ^ ln7) * 8)]; \
      lacc = __builtin_amdgcn_mfma_f32_32x32x16_bf16(pu.s8, ones8, lacc, 0, 0, 0);       \
      oacc0 = __builtin_amdgcn_mfma_f32_32x32x16_bf16(pu.s8, vb0, oacc0, 0, 0, 0);       \
      oacc1 = __builtin_amdgcn_mfma_f32_32x32x16_bf16(pu.s8, vb1, oacc1, 0, 0, 0);       \
    }                                                                                    \
    __builtin_amdgcn_s_setprio(0);                                                       \
  }

__global__ __launch_bounds__(256, 4) void k_attn(const unsigned short* __restrict__ Qb,
                                                 const unsigned short* __restrict__ Kb,
                                                 const unsigned short* __restrict__ Vt,
                                                 unsigned short* __restrict__ Xh) {
  int bh = blockIdx.x;  // 24
  int qb = blockIdx.y;  // 32
  int b = bh / 12, h = bh - b * 12;
  __shared__ __align__(16) unsigned short LDSbuf[4 * 64 * 64];
  unsigned short* Ks0 = LDSbuf;
  unsigned short* Vs0 = LDSbuf + 64 * 64;
  unsigned short* Ks1 = LDSbuf + 2 * 64 * 64;
  unsigned short* Vs1 = LDSbuf + 3 * 64 * 64;
  int tid = threadIdx.x;
  int wid = tid >> 6, lane = tid & 63;
  int qh = wid >> 1, kh = wid & 1;
  int ln31 = lane & 31, hi = lane >> 5, ln7 = lane & 7;
  int khead = bh * 2048;
  int vhead = bh * 64;
  int q0 = qb * 64 + qh * 32;

  short8 qf[4];
#pragma unroll
  for (int ds = 0; ds < 4; ++ds)
    qf[ds] = *(const short8*)&Qb[(size_t)(khead + q0 + ln31) * 64 + ds * 16 + hi * 8];

  short8 ones8;
#pragma unroll
  for (int j = 0; j < 8; ++j) ones8[j] = (short)0x3F80;  // bf16 1.0

  f32x16 oacc0 = {}, oacc1 = {}, lacc = {};

  ATTN_STAGE(Ks0, Vs0, 0);
  __syncthreads();
#pragma unroll 1
  for (int tt = 0; tt < 16; ++tt) {
    ATTN_STAGE(Ks1, Vs1, 2 * tt + 1);
    PROC_TILE(Ks0, Vs0);
    __syncthreads();
    if (tt < 15) ATTN_STAGE(Ks0, Vs0, 2 * tt + 2);
    PROC_TILE(Ks1, Vs1);
    __syncthreads();
  }

  // merge kh pairs via LDS scratch (reuse staging buffers)
  float* scr = (float*)LDSbuf;  // [2 qh][64 lane][49]
  if (kh == 1) {
    float* p = scr + (size_t)(qh * 64 + lane) * 49;
#pragma unroll
    for (int i = 0; i < 16; ++i) {
      p[i] = oacc0[i];
      p[16 + i] = oacc1[i];
      p[32 + i] = lacc[i];
    }
  }
  __syncthreads();
  if (kh == 0) {
    float* p = scr + (size_t)(qh * 64 + lane) * 49;
#pragma unroll
    for (int r = 0; r < 16; ++r) {
      float o0 = oacc0[r] + p[r];
      float o1 = oacc1[r] + p[16 + r];
      float linv = 1.0f / (lacc[r] + p[32 + r]);
      int qrow = (r & 3) + 8 * (r >> 2) + 4 * hi;
      int grow = b * 2048 + q0 + qrow;
      int colb = h * 64 + ln31;
      Xh[(size_t)grow * 768 + colb] = f32_to_bf16(o0 * linv);
      Xh[(size_t)grow * 768 + colb + 32] = f32_to_bf16(o1 * linv);
    }
  }
}

// ---------------- launch ----------------
extern "C" void kernel_launch(void* const* d_in, const int* in_sizes, int n_in,
                              void* d_out, int out_size, void* d_ws, size_t ws_size,
                              hipStream_t stream) {
  const float* x = (const float*)d_in[0];      // [2,2048,768]
  const float* W_qkv = (const float*)d_in[1];  // [768,2304]
  const float* b_qkv = (const float*)d_in[2];  // [2304]
  const float* W_out = (const float*)d_in[3];  // [768,768]
  const float* b_out = (const float*)d_in[4];  // [768]
  float* out = (float*)d_out;                  // [4096,768]
  char* ws = (char*)d_ws;

  unsigned short* Xh = (unsigned short*)(ws + 0);           // 4096x768 bf16 (attn out H)
  unsigned short* Xb = (unsigned short*)(ws + 18874368);    // 4096x768 bf16 (x cast)
  unsigned short* Wq_t = (unsigned short*)(ws + 25165824);  // 2304x768 bf16
  unsigned short* Wo_t = (unsigned short*)(ws + 28704768);  // 768x768 bf16
  unsigned short* Qb = (unsigned short*)(ws + 32243712);    // 24x2048x64 (pre-scaled)
  unsigned short* Kb = (unsigned short*)(ws + 38535168);    // 24x2048x64
  unsigned short* Vt = (unsigned short*)(ws + 51118080);    // 24x64x2048

  k_prep<<<3840, 256, 0, stream>>>(x, W_qkv, W_out, Xb, Wq_t, Wo_t);
  k_gemm_qkv<<<dim3(32, 36), 256, 0, stream>>>(Xb, Wq_t, b_qkv, 4096, 2304, 768, Qb, Kb, Vt);
  k_attn<<<dim3(24, 32), 256, 0, stream>>>(Qb, Kb, Vt, Xh);
  k_gemm2<<<dim3(64, 12), 256, 0, stream>>>(Xh, Wo_t, b_out, out, 4096, 768, 768);
}